// Round 1
// baseline (48692.236 us; speedup 1.0000x reference)
//
#include <hip/hip_runtime.h>
#include <hip/hip_cooperative_groups.h>
#include <math.h>

namespace cg = cooperative_groups;

constexpr int Bn = 64;
constexpr int Tn = 512;
constexpr int Hn = 768;
constexpr int RTn = Bn * Tn;               // 32768 rows

// workspace offsets (in floats)
constexpr size_t OFF_XP   = 0;
constexpr size_t OFF_H12  = OFF_XP  + (size_t)RTn * Hn;    // 25165824
constexpr size_t OFF_TAGX = OFF_H12 + (size_t)RTn * Hn;    // 50331648
constexpr size_t OFF_C12  = OFF_TAGX + (size_t)RTn;        // +32768
constexpr size_t OFF_H1B0 = OFF_C12  + (size_t)Hn;
constexpr size_t OFF_H1B1 = OFF_H1B0 + (size_t)Bn * Hn;
constexpr size_t OFF_H2B0 = OFF_H1B1 + (size_t)Bn * Hn;
constexpr size_t OFF_H2B1 = OFF_H2B0 + (size_t)Bn * Hn;

// ---------------------------------------------------------------------------
// c12[j] = b12[j] + sum_e W_hh12[j][e] * h_init[e]
__global__ void __launch_bounds__(256) c12_kernel(const float* __restrict__ Whh12,
                                                  const float* __restrict__ hinit,
                                                  const float* __restrict__ b12,
                                                  float* __restrict__ c12) {
    int j = blockIdx.x * 256 + threadIdx.x;
    if (j >= Hn) return;
    float s = b12[j];
    const float* row = Whh12 + (size_t)j * Hn;
    for (int e = 0; e < Hn; ++e) s += row[e] * hinit[e];
    c12[j] = s;
}

// ---------------------------------------------------------------------------
// tag_x[r] = sum_e bert[r][e] * W_tag[2H + e] + b_tag     (one wave per row)
__global__ void __launch_bounds__(256) tagx_kernel(const float* __restrict__ bert,
                                                   const float* __restrict__ Wtag,
                                                   const float* __restrict__ btag,
                                                   float* __restrict__ tagx) {
    int r = blockIdx.x * 4 + (threadIdx.x >> 6);
    int lane = threadIdx.x & 63;
    const float* wx = Wtag + 2 * Hn;
    const float* row = bert + (size_t)r * Hn;
    float s = 0.f;
    for (int e = lane; e < Hn; e += 64) s += row[e] * wx[e];
    #pragma unroll
    for (int m = 1; m < 64; m <<= 1) s += __shfl_xor(s, m, 64);
    if (lane == 0) tagx[r] = s + btag[0];
}

// ---------------------------------------------------------------------------
// Precompute GEMM over 1536 virtual output cols:
//   col n <  768: xp11[r][n] = bert[r]·W_ih11[n] + b11[n]
//   col n >= 768: h12 [r][n-768] = tanh(bert[r]·W_ih12[n-768] + c12[n-768])
// Tile 128x64, BK=16, 256 threads, 8x4 microtile. fp32.
__global__ void __launch_bounds__(256) gemm_pre(const float* __restrict__ bert,
                                                const float* __restrict__ Wih11,
                                                const float* __restrict__ Wih12,
                                                const float* __restrict__ b11,
                                                const float* __restrict__ c12,
                                                float* __restrict__ xp,
                                                float* __restrict__ h12) {
    constexpr int BM = 128, BN = 64, BK = 16;
    __shared__ float As[BK][BM];
    __shared__ float Ws[BK][BN];
    const int bid = blockIdx.x;
    const int mt = bid / 24, nt = bid % 24;
    const int r0 = mt * BM;
    const int n0 = nt * BN;
    const bool second = (n0 >= Hn);
    const float* W = second ? Wih12 : Wih11;
    const int jbase = second ? (n0 - Hn) : n0;
    const int tid = threadIdx.x;
    const int ty = tid >> 4, tx = tid & 15;
    const int lrow = tid >> 1, lhalf = (tid & 1) * 8;
    const int wjl = tid & 63, wkk = tid >> 6;
    float acc[8][4] = {};
    for (int e0 = 0; e0 < Hn; e0 += BK) {
        float4 av0 = *(const float4*)(bert + (size_t)(r0 + lrow) * Hn + e0 + lhalf);
        float4 av1 = *(const float4*)(bert + (size_t)(r0 + lrow) * Hn + e0 + lhalf + 4);
        float4 wv  = *(const float4*)(W + (size_t)(jbase + wjl) * Hn + e0 + wkk * 4);
        As[lhalf + 0][lrow] = av0.x; As[lhalf + 1][lrow] = av0.y;
        As[lhalf + 2][lrow] = av0.z; As[lhalf + 3][lrow] = av0.w;
        As[lhalf + 4][lrow] = av1.x; As[lhalf + 5][lrow] = av1.y;
        As[lhalf + 6][lrow] = av1.z; As[lhalf + 7][lrow] = av1.w;
        Ws[wkk * 4 + 0][wjl] = wv.x; Ws[wkk * 4 + 1][wjl] = wv.y;
        Ws[wkk * 4 + 2][wjl] = wv.z; Ws[wkk * 4 + 3][wjl] = wv.w;
        __syncthreads();
        #pragma unroll
        for (int k = 0; k < BK; ++k) {
            float a[8], w[4];
            *(float4*)&a[0] = *(const float4*)&As[k][ty * 8];
            *(float4*)&a[4] = *(const float4*)&As[k][ty * 8 + 4];
            *(float4*)&w[0] = *(const float4*)&Ws[k][tx * 4];
            #pragma unroll
            for (int ii = 0; ii < 8; ++ii)
                #pragma unroll
                for (int jj = 0; jj < 4; ++jj)
                    acc[ii][jj] += a[ii] * w[jj];
        }
        __syncthreads();
    }
    #pragma unroll
    for (int ii = 0; ii < 8; ++ii) {
        size_t r = (size_t)(r0 + ty * 8 + ii);
        if (!second) {
            #pragma unroll
            for (int jj = 0; jj < 4; ++jj) {
                int n = n0 + tx * 4 + jj;
                xp[r * Hn + n] = acc[ii][jj] + b11[n];
            }
        } else {
            #pragma unroll
            for (int jj = 0; jj < 4; ++jj) {
                int n = n0 - Hn + tx * 4 + jj;
                h12[r * Hn + n] = tanhf(acc[ii][jj] + c12[n]);
            }
        }
    }
}

// ---------------------------------------------------------------------------
// Persistent cooperative scan. 192 WGs = 8 batch-groups(8 batches) x 24
// col-groups(32 cols). Thread (bl,c): batch b = bg*8+bl, col j = cgp*32+c.
// Per step: stage h1/h2 tiles to LDS, compute tag gate (redundant per
// col-group, 32-lane shfl reduce), 3 dot-768s per thread, gate, write.
__global__ void __launch_bounds__(256, 1) scan_kernel(
        const float* __restrict__ xp, const float* __restrict__ h12,
        const float* __restrict__ tagx,
        const float* __restrict__ Whh11, const float* __restrict__ Wih21,
        const float* __restrict__ Whh21, const float* __restrict__ b21,
        const float* __restrict__ Wtag,
        float* __restrict__ h1b0, float* __restrict__ h1b1,
        float* __restrict__ h2b0, float* __restrict__ h2b1,
        float* __restrict__ out) {
    cg::grid_group grid = cg::this_grid();
    __shared__ float h1s[8][Hn];
    __shared__ float h2s[8][Hn];
    __shared__ float wt1[Hn], wt2[Hn];
    const int tid = threadIdx.x;
    const int bg  = blockIdx.x / 24;   // 0..7
    const int cgp = blockIdx.x % 24;   // 0..23
    const int bl  = tid >> 5;          // 0..7
    const int c   = tid & 31;          // 0..31
    const int b   = bg * 8 + bl;       // global batch
    const int j   = cgp * 32 + c;      // global col
    for (int i = tid; i < Hn; i += 256) { wt1[i] = Wtag[i]; wt2[i] = Wtag[Hn + i]; }
    const float* w11  = Whh11 + (size_t)j * Hn;
    const float* w21a = Wih21 + (size_t)j * Hn;
    const float* w21b = Whh21 + (size_t)j * Hn;
    const float bias21 = b21[j];
    float* outh2  = out + RTn;
    float* outtag = out + RTn + (size_t)RTn * Hn;

    for (int t = 0; t < Tn; ++t) {
        const float* h1c = (t & 1) ? h1b1 : h1b0;
        const float* h2c = (t & 1) ? h2b1 : h2b0;
        float* h1n = (t & 1) ? h1b0 : h1b1;
        float* h2n = (t & 1) ? h2b0 : h2b1;
        // stage this batch-group's h tiles (8 x 768 each)
        {
            const float4* s1 = (const float4*)(h1c + (size_t)bg * 8 * Hn);
            const float4* s2 = (const float4*)(h2c + (size_t)bg * 8 * Hn);
            float4* d1 = (float4*)(&h1s[0][0]);
            float4* d2 = (float4*)(&h2s[0][0]);
            #pragma unroll
            for (int i = 0; i < 6; ++i) {
                d1[tid + i * 256] = s1[tid + i * 256];
                d2[tid + i * 256] = s2[tid + i * 256];
            }
        }
        __syncthreads();
        // tag gate: partial over 24 cols per lane, reduce across 32 lanes
        float tp = 0.f;
        #pragma unroll
        for (int q = 0; q < 24; ++q) {
            int jj = c * 24 + q;
            tp += h1s[bl][jj] * wt1[jj] + h2s[bl][jj] * wt2[jj];
        }
        #pragma unroll
        for (int m = 1; m < 32; m <<= 1) tp += __shfl_xor(tp, m, 64);
        const float tag = tagx[(size_t)b * Tn + t] + tp;
        const float o = 1.f / (1.f + expf(-tag));
        // three dot-768s: h1·W_hh11[j], h1·W_ih21[j] + h2·W_hh21[j]
        float a11 = 0.f, a21 = 0.f;
        #pragma unroll 4
        for (int k = 0; k < Hn; k += 4) {
            float4 x1 = *(const float4*)&h1s[bl][k];
            float4 x2 = *(const float4*)&h2s[bl][k];
            float4 u = *(const float4*)&w11[k];
            float4 v = *(const float4*)&w21a[k];
            float4 w = *(const float4*)&w21b[k];
            a11 += x1.x * u.x + x1.y * u.y + x1.z * u.z + x1.w * u.w;
            a21 += x1.x * v.x + x1.y * v.y + x1.z * v.z + x1.w * v.w;
            a21 += x2.x * w.x + x2.y * w.y + x2.z * w.z + x2.w * w.w;
        }
        const size_t rr = (size_t)b * Tn + t;
        const float h11  = tanhf(xp[rr * Hn + j] + a11);
        const float h21  = tanhf(a21 + bias21);
        const float h12v = h12[rr * Hn + j];
        const float h2p  = h2s[bl][j];
        const float h1nv = h11 * (1.f - o) + h12v * o;
        const float h2nv = h2p * (1.f - o) + h21 * o;
        h1n[(size_t)b * Hn + j] = h1nv;
        h2n[(size_t)b * Hn + j] = h2nv;
        outh2[rr * Hn + j] = h2nv;
        if (cgp == 0 && c == 0) { out[rr] = o; outtag[rr] = tag; }
        grid.sync();
    }
}

// ---------------------------------------------------------------------------
extern "C" void kernel_launch(void* const* d_in, const int* in_sizes, int n_in,
                              void* d_out, int out_size, void* d_ws, size_t ws_size,
                              hipStream_t stream) {
    const float* bert  = (const float*)d_in[0];
    const float* Wih11 = (const float*)d_in[1];
    const float* Whh11 = (const float*)d_in[2];
    const float* b11   = (const float*)d_in[3];
    const float* Wih12 = (const float*)d_in[4];
    const float* Whh12 = (const float*)d_in[5];
    const float* b12   = (const float*)d_in[6];
    const float* Wih21 = (const float*)d_in[7];
    const float* Whh21 = (const float*)d_in[8];
    const float* b21   = (const float*)d_in[9];
    const float* Wtag  = (const float*)d_in[10];
    const float* btag  = (const float*)d_in[11];
    const float* hinit = (const float*)d_in[12];
    float* ws = (float*)d_ws;
    float* xp   = ws + OFF_XP;
    float* h12  = ws + OFF_H12;
    float* tagx = ws + OFF_TAGX;
    float* c12  = ws + OFF_C12;
    float* h1b0 = ws + OFF_H1B0;
    float* h1b1 = ws + OFF_H1B1;
    float* h2b0 = ws + OFF_H2B0;
    float* h2b1 = ws + OFF_H2B1;
    float* out  = (float*)d_out;

    // zero initial hidden states (ping-pong buf 0)
    hipMemsetAsync(h1b0, 0, (size_t)Bn * Hn * sizeof(float), stream);
    hipMemsetAsync(h2b0, 0, (size_t)Bn * Hn * sizeof(float), stream);

    c12_kernel<<<3, 256, 0, stream>>>(Whh12, hinit, b12, c12);
    gemm_pre<<<256 * 24, 256, 0, stream>>>(bert, Wih11, Wih12, b11, c12, xp, h12);
    tagx_kernel<<<RTn / 4, 256, 0, stream>>>(bert, Wtag, btag, tagx);

    void* params[] = { &xp, &h12, &tagx, &Whh11, &Wih21, &Whh21, &b21, &Wtag,
                       &h1b0, &h1b1, &h2b0, &h2b1, &out };
    hipLaunchCooperativeKernel((void*)scan_kernel, dim3(192), dim3(256),
                               params, 0, stream);
}

// Round 3
// 22986.659 us; speedup vs baseline: 2.1183x; 2.1183x over previous
//
#include <hip/hip_runtime.h>
#include <hip/hip_cooperative_groups.h>
#include <math.h>

namespace cg = cooperative_groups;

constexpr int Bn = 64;
constexpr int Tn = 512;
constexpr int Hn = 768;
constexpr int RTn = Bn * Tn;               // 32768 rows

// workspace offsets (in floats)
constexpr size_t OFF_XP   = 0;
constexpr size_t OFF_H12  = OFF_XP  + (size_t)RTn * Hn;
constexpr size_t OFF_TAGX = OFF_H12 + (size_t)RTn * Hn;
constexpr size_t OFF_C12  = OFF_TAGX + (size_t)RTn;
constexpr size_t OFF_H1B0 = OFF_C12  + Hn;
constexpr size_t OFF_H1B1 = OFF_H1B0 + (size_t)Bn * Hn;
constexpr size_t OFF_H2B0 = OFF_H1B1 + (size_t)Bn * Hn;
constexpr size_t OFF_H2B1 = OFF_H2B0 + (size_t)Bn * Hn;

// ---------------------------------------------------------------------------
__global__ void __launch_bounds__(256) c12_kernel(const float* __restrict__ Whh12,
                                                  const float* __restrict__ hinit,
                                                  const float* __restrict__ b12,
                                                  float* __restrict__ c12) {
    int j = blockIdx.x * 256 + threadIdx.x;
    if (j >= Hn) return;
    float s = b12[j];
    const float* row = Whh12 + (size_t)j * Hn;
    for (int e = 0; e < Hn; ++e) s += row[e] * hinit[e];
    c12[j] = s;
}

// ---------------------------------------------------------------------------
__global__ void __launch_bounds__(256) tagx_kernel(const float* __restrict__ bert,
                                                   const float* __restrict__ Wtag,
                                                   const float* __restrict__ btag,
                                                   float* __restrict__ tagx) {
    int r = blockIdx.x * 4 + (threadIdx.x >> 6);
    int lane = threadIdx.x & 63;
    const float* wx = Wtag + 2 * Hn;
    const float* row = bert + (size_t)r * Hn;
    float s = 0.f;
    for (int e = lane; e < Hn; e += 64) s += row[e] * wx[e];
    #pragma unroll
    for (int m = 1; m < 64; m <<= 1) s += __shfl_xor(s, m, 64);
    if (lane == 0) tagx[r] = s + btag[0];
}

// ---------------------------------------------------------------------------
// Precompute GEMM (fp32): xp11 and tanh'ed h12_seq.  (identical to R1)
__global__ void __launch_bounds__(256) gemm_pre(const float* __restrict__ bert,
                                                const float* __restrict__ Wih11,
                                                const float* __restrict__ Wih12,
                                                const float* __restrict__ b11,
                                                const float* __restrict__ c12,
                                                float* __restrict__ xp,
                                                float* __restrict__ h12) {
    constexpr int BM = 128, BN = 64, BK = 16;
    __shared__ float As[BK][BM];
    __shared__ float Ws[BK][BN];
    const int bid = blockIdx.x;
    const int mt = bid / 24, nt = bid % 24;
    const int r0 = mt * BM;
    const int n0 = nt * BN;
    const bool second = (n0 >= Hn);
    const float* W = second ? Wih12 : Wih11;
    const int jbase = second ? (n0 - Hn) : n0;
    const int tid = threadIdx.x;
    const int ty = tid >> 4, tx = tid & 15;
    const int lrow = tid >> 1, lhalf = (tid & 1) * 8;
    const int wjl = tid & 63, wkk = tid >> 6;
    float acc[8][4] = {};
    for (int e0 = 0; e0 < Hn; e0 += BK) {
        float4 av0 = *(const float4*)(bert + (size_t)(r0 + lrow) * Hn + e0 + lhalf);
        float4 av1 = *(const float4*)(bert + (size_t)(r0 + lrow) * Hn + e0 + lhalf + 4);
        float4 wv  = *(const float4*)(W + (size_t)(jbase + wjl) * Hn + e0 + wkk * 4);
        As[lhalf + 0][lrow] = av0.x; As[lhalf + 1][lrow] = av0.y;
        As[lhalf + 2][lrow] = av0.z; As[lhalf + 3][lrow] = av0.w;
        As[lhalf + 4][lrow] = av1.x; As[lhalf + 5][lrow] = av1.y;
        As[lhalf + 6][lrow] = av1.z; As[lhalf + 7][lrow] = av1.w;
        Ws[wkk * 4 + 0][wjl] = wv.x; Ws[wkk * 4 + 1][wjl] = wv.y;
        Ws[wkk * 4 + 2][wjl] = wv.z; Ws[wkk * 4 + 3][wjl] = wv.w;
        __syncthreads();
        #pragma unroll
        for (int k = 0; k < BK; ++k) {
            float a[8], w[4];
            *(float4*)&a[0] = *(const float4*)&As[k][ty * 8];
            *(float4*)&a[4] = *(const float4*)&As[k][ty * 8 + 4];
            *(float4*)&w[0] = *(const float4*)&Ws[k][tx * 4];
            #pragma unroll
            for (int ii = 0; ii < 8; ++ii)
                #pragma unroll
                for (int jj = 0; jj < 4; ++jj)
                    acc[ii][jj] += a[ii] * w[jj];
        }
        __syncthreads();
    }
    #pragma unroll
    for (int ii = 0; ii < 8; ++ii) {
        size_t r = (size_t)(r0 + ty * 8 + ii);
        if (!second) {
            #pragma unroll
            for (int jj = 0; jj < 4; ++jj) {
                int n = n0 + tx * 4 + jj;
                xp[r * Hn + n] = acc[ii][jj] + b11[n];
            }
        } else {
            #pragma unroll
            for (int jj = 0; jj < 4; ++jj) {
                int n = n0 - Hn + tx * 4 + jj;
                h12[r * Hn + n] = tanhf(acc[ii][jj] + c12[n]);
            }
        }
    }
}

// ---------------------------------------------------------------------------
// fp32 register-weight scan. 192 blocks = 4 batch-groups(16) x 48 col-groups
// (16 cols). Thread (j = tid&15, ks = tid>>4) holds W[col][ks*48..+47] for 3
// matrices in 36 float4 registers. State is fp32 in global ping-pong buffers
// (exact R1 math). Per step: flat-stage state to LDS, gate via 16-way k-split
// + shfl reduce, per-batch dot-48 partials, xor(16,32) in-wave reduce +
// 4-wave LDS reduce, wave-0 fp32 epilogue with register h2 carry.
__global__ void __launch_bounds__(256, 1) scan_kernel(
        const float* __restrict__ xp, const float* __restrict__ h12,
        const float* __restrict__ tagx,
        const float* __restrict__ Whh11, const float* __restrict__ Wih21,
        const float* __restrict__ Whh21, const float* __restrict__ b21,
        const float* __restrict__ Wtag,
        float* __restrict__ h1b0, float* __restrict__ h1b1,
        float* __restrict__ h2b0, float* __restrict__ h2b1,
        float* __restrict__ out) {
    cg::grid_group grid = cg::this_grid();
    __shared__ float h1s[16 * Hn];          // 48 KB, flat, stride 768
    __shared__ float h2s[16 * Hn];          // 48 KB
    __shared__ float wt1[Hn], wt2[Hn];
    __shared__ float redbuf[4][16][2][16];  // [wave][batch][{a11,a21}][j]
    __shared__ float tagbuf[16];

    const int tid  = threadIdx.x;
    const int wv   = tid >> 6;          // wave 0..3
    const int lane = tid & 63;
    const int j    = lane & 15;         // col-local 0..15
    const int ksl  = lane >> 4;         // k-slice within wave 0..3
    const int ks   = wv * 4 + ksl;      // k-slice 0..15 -> k in [ks*48, ks*48+48)
    const int kb   = ks * 48;
    const int bgp  = blockIdx.x / 48;   // batch group 0..3
    const int cgp  = blockIdx.x % 48;   // col group 0..47
    const int col  = cgp * 16 + j;

    // ---- loop-invariant: weight slices into registers (36 float4) ----
    float4 w11r[12], w21r[12], w2hr[12];
    {
        const float* p1 = Whh11 + (size_t)col * Hn + kb;
        const float* p2 = Wih21 + (size_t)col * Hn + kb;
        const float* p3 = Whh21 + (size_t)col * Hn + kb;
        #pragma unroll
        for (int q = 0; q < 12; ++q) {
            w11r[q] = *(const float4*)(p1 + q * 4);
            w21r[q] = *(const float4*)(p2 + q * 4);
            w2hr[q] = *(const float4*)(p3 + q * 4);
        }
    }
    for (int i = tid; i < Hn; i += 256) { wt1[i] = Wtag[i]; wt2[i] = Wtag[Hn + i]; }
    const float bias21 = b21[col];

    const int gp  = lane & 15;          // gate: k-partial id
    const int gm  = wv * 4 + (lane >> 4); // gate: batch 0..15

    float h2carry[4] = {0.f, 0.f, 0.f, 0.f};
    float* outO   = out;
    float* outH2  = out + RTn;
    float* outTag = out + RTn + (size_t)RTn * Hn;
    const size_t srcbase = (size_t)bgp * 16 * Hn;
    __syncthreads();

    for (int t = 0; t < Tn; ++t) {
        const float* h1c = (t & 1) ? h1b1 : h1b0;
        const float* h2c = (t & 1) ? h2b1 : h2b0;
        float* h1n = (t & 1) ? h1b0 : h1b1;
        float* h2n = (t & 1) ? h2b0 : h2b1;

        // wave-0 prefetch of xp/h12 for this step's tile
        float xpv[4], h12pv[4];
        if (wv == 0) {
            #pragma unroll
            for (int r = 0; r < 4; ++r) {
                int m = ksl * 4 + r;
                size_t rr = (size_t)(bgp * 16 + m) * Tn + t;
                xpv[r]   = xp [rr * Hn + col];
                h12pv[r] = h12[rr * Hn + col];
            }
        }

        // phase A: flat-stage h1,h2 (16 x 768 fp32 each) into LDS
        #pragma unroll
        for (int i = 0; i < 12; ++i) {
            int c4 = (tid + i * 256) * 4;
            *(float4*)&h1s[c4] = *(const float4*)(h1c + srcbase + c4);
            *(float4*)&h2s[c4] = *(const float4*)(h2c + srcbase + c4);
        }
        __syncthreads();

        // phase B: tag gate for batch gm; thread covers k = gp*4 + q*64
        {
            float s0 = 0.f, s1 = 0.f, s2 = 0.f, s3 = 0.f;
            #pragma unroll
            for (int q = 0; q < 12; ++q) {
                int off = gp * 4 + q * 64;
                float4 x1 = *(const float4*)&h1s[gm * Hn + off];
                float4 x2 = *(const float4*)&h2s[gm * Hn + off];
                float4 u1 = *(const float4*)&wt1[off];
                float4 u2 = *(const float4*)&wt2[off];
                s0 = fmaf(x1.x, u1.x, s0); s1 = fmaf(x1.y, u1.y, s1);
                s2 = fmaf(x1.z, u1.z, s2); s3 = fmaf(x1.w, u1.w, s3);
                s0 = fmaf(x2.x, u2.x, s0); s1 = fmaf(x2.y, u2.y, s1);
                s2 = fmaf(x2.z, u2.z, s2); s3 = fmaf(x2.w, u2.w, s3);
            }
            float s = (s0 + s1) + (s2 + s3);
            s += __shfl_xor(s, 1, 64); s += __shfl_xor(s, 2, 64);
            s += __shfl_xor(s, 4, 64); s += __shfl_xor(s, 8, 64);
            if (gp == 0)
                tagbuf[gm] = tagx[(size_t)(bgp * 16 + gm) * Tn + t] + s;
        }

        // phase C: matvec partials per batch (register weights)
        #pragma unroll 2
        for (int b = 0; b < 16; ++b) {
            const float* r1 = &h1s[b * Hn + kb];
            const float* r2 = &h2s[b * Hn + kb];
            float a0 = 0.f, a1 = 0.f, a2 = 0.f, a3 = 0.f;   // a11 comps
            float c0 = 0.f, c1 = 0.f, c2 = 0.f, c3 = 0.f;   // a21 (h1 part)
            float d0 = 0.f, d1 = 0.f, d2 = 0.f, d3 = 0.f;   // a21 (h2 part)
            #pragma unroll
            for (int q = 0; q < 12; ++q) {
                float4 x1 = *(const float4*)(r1 + q * 4);
                float4 x2 = *(const float4*)(r2 + q * 4);
                a0 = fmaf(x1.x, w11r[q].x, a0); a1 = fmaf(x1.y, w11r[q].y, a1);
                a2 = fmaf(x1.z, w11r[q].z, a2); a3 = fmaf(x1.w, w11r[q].w, a3);
                c0 = fmaf(x1.x, w21r[q].x, c0); c1 = fmaf(x1.y, w21r[q].y, c1);
                c2 = fmaf(x1.z, w21r[q].z, c2); c3 = fmaf(x1.w, w21r[q].w, c3);
                d0 = fmaf(x2.x, w2hr[q].x, d0); d1 = fmaf(x2.y, w2hr[q].y, d1);
                d2 = fmaf(x2.z, w2hr[q].z, d2); d3 = fmaf(x2.w, w2hr[q].w, d3);
            }
            float a11 = (a0 + a1) + (a2 + a3);
            float a21 = ((c0 + c1) + (c2 + c3)) + ((d0 + d1) + (d2 + d3));
            a11 += __shfl_xor(a11, 16, 64); a11 += __shfl_xor(a11, 32, 64);
            a21 += __shfl_xor(a21, 16, 64); a21 += __shfl_xor(a21, 32, 64);
            if (ksl == 0) {
                redbuf[wv][b][0][j] = a11;
                redbuf[wv][b][1][j] = a21;
            }
        }
        __syncthreads();

        // phase D: wave 0 combines, gates, updates, writes
        if (wv == 0) {
            #pragma unroll
            for (int r = 0; r < 4; ++r) {
                int m = ksl * 4 + r;
                int b = bgp * 16 + m;
                float f11 = redbuf[0][m][0][j] + redbuf[1][m][0][j]
                          + redbuf[2][m][0][j] + redbuf[3][m][0][j];
                float f21 = redbuf[0][m][1][j] + redbuf[1][m][1][j]
                          + redbuf[2][m][1][j] + redbuf[3][m][1][j];
                float tg = tagbuf[m];
                float o  = 1.f / (1.f + expf(-tg));
                float h11v = tanhf(xpv[r] + f11);
                float h21v = tanhf(f21 + bias21);
                float h1nv = h11v * (1.f - o) + h12pv[r] * o;
                float h2nv = h2carry[r] * (1.f - o) + h21v * o;
                h2carry[r] = h2nv;
                size_t rr = (size_t)b * Tn + t;
                h1n[(size_t)b * Hn + col] = h1nv;
                h2n[(size_t)b * Hn + col] = h2nv;
                outH2[rr * Hn + col] = h2nv;
            }
            if (lane < 16 && cgp == 0) {
                float tg = tagbuf[lane];
                size_t rr = (size_t)(bgp * 16 + lane) * Tn + t;
                outO[rr]   = 1.f / (1.f + expf(-tg));
                outTag[rr] = tg;
            }
        }
        grid.sync();
    }
}

// ---------------------------------------------------------------------------
extern "C" void kernel_launch(void* const* d_in, const int* in_sizes, int n_in,
                              void* d_out, int out_size, void* d_ws, size_t ws_size,
                              hipStream_t stream) {
    const float* bert  = (const float*)d_in[0];
    const float* Wih11 = (const float*)d_in[1];
    const float* Whh11 = (const float*)d_in[2];
    const float* b11   = (const float*)d_in[3];
    const float* Wih12 = (const float*)d_in[4];
    const float* Whh12 = (const float*)d_in[5];
    const float* b12   = (const float*)d_in[6];
    const float* Wih21 = (const float*)d_in[7];
    const float* Whh21 = (const float*)d_in[8];
    const float* b21   = (const float*)d_in[9];
    const float* Wtag  = (const float*)d_in[10];
    const float* btag  = (const float*)d_in[11];
    const float* hinit = (const float*)d_in[12];
    float* ws = (float*)d_ws;
    float* xp   = ws + OFF_XP;
    float* h12  = ws + OFF_H12;
    float* tagx = ws + OFF_TAGX;
    float* c12  = ws + OFF_C12;
    float* h1b0 = ws + OFF_H1B0;
    float* h1b1 = ws + OFF_H1B1;
    float* h2b0 = ws + OFF_H2B0;
    float* h2b1 = ws + OFF_H2B1;
    float* out  = (float*)d_out;

    hipMemsetAsync(h1b0, 0, (size_t)Bn * Hn * sizeof(float), stream);
    hipMemsetAsync(h2b0, 0, (size_t)Bn * Hn * sizeof(float), stream);

    c12_kernel<<<3, 256, 0, stream>>>(Whh12, hinit, b12, c12);
    gemm_pre<<<256 * 24, 256, 0, stream>>>(bert, Wih11, Wih12, b11, c12, xp, h12);
    tagx_kernel<<<RTn / 4, 256, 0, stream>>>(bert, Wtag, btag, tagx);

    void* params[] = { &xp, &h12, &tagx, &Whh11, &Wih21, &Whh21, &b21, &Wtag,
                       &h1b0, &h1b1, &h2b0, &h2b1, &out };
    hipLaunchCooperativeKernel((void*)scan_kernel, dim3(192), dim3(256),
                               params, 0, stream);
}